// Round 4
// baseline (207.464 us; speedup 1.0000x reference)
//
#include <hip/hip_runtime.h>
#include <stdint.h>

#define B_ROWS 4096
#define D_IN   2048
#define D_OUT  2048
#define KANCH  4

typedef _Float16 half8  __attribute__((ext_vector_type(8)));
typedef _Float16 half4  __attribute__((ext_vector_type(4)));
typedef float    floatx4 __attribute__((ext_vector_type(4)));
typedef const __attribute__((address_space(1))) uint8_t* gptr_t;
typedef __attribute__((address_space(3))) uint8_t* lptr_t;

// K1 fused prep:
//  blocks [0,1024): convert x->fp16, n2x[b]=||x_b||^2, one atomicAdd of block's
//                   4 softplus(x_b.cw+cb) partials into scal[0]
//  blocks [1024,2048): convert W->fp16
__global__ __launch_bounds__(256) void k_prep(
    const float* __restrict__ x,
    const float* __restrict__ W,
    const float* __restrict__ cw,
    const float* __restrict__ cb,
    _Float16* __restrict__ xh,
    _Float16* __restrict__ Wh,
    float* __restrict__ n2x,
    float* __restrict__ scal)
{
    int tid = threadIdx.x;
    if (blockIdx.x < 1024) {
        int w = tid >> 6, lane = tid & 63;
        int row = blockIdx.x * 4 + w;
        const floatx4* xr = (const floatx4*)(x + (size_t)row * D_IN);
        const floatx4* wr = (const floatx4*)cw;
        _Float16* xo = xh + (size_t)row * D_IN;
        float dot = 0.f, ss = 0.f;
#pragma unroll
        for (int i = 0; i < 8; ++i) {
            int idx = i * 64 + lane;
            floatx4 xv = xr[idx];
            floatx4 wv = wr[idx];
#pragma unroll
            for (int j = 0; j < 4; ++j) {
                dot += xv[j] * wv[j];
                ss  += xv[j] * xv[j];
            }
            half4 h = {(_Float16)xv[0], (_Float16)xv[1], (_Float16)xv[2], (_Float16)xv[3]};
            *(half4*)(xo + idx * 4) = h;
        }
#pragma unroll
        for (int off = 32; off; off >>= 1) {
            dot += __shfl_down(dot, off);
            ss  += __shfl_down(ss, off);
        }
        __shared__ float spw[4];
        if (lane == 0) {
            n2x[row] = ss;
            float z = dot + cb[0];
            spw[w] = (z > 20.f) ? z : log1pf(expf(z));
        }
        __syncthreads();
        if (tid == 0)
            atomicAdd(&scal[0], spw[0] + spw[1] + spw[2] + spw[3]);
    } else {
        int blk = blockIdx.x - 1024;
        const floatx4* W4 = (const floatx4*)W;
#pragma unroll
        for (int i = 0; i < 4; ++i) {
            int idx = blk * 1024 + i * 256 + tid;   // float4 index
            floatx4 v = W4[idx];
            half4 h = {(_Float16)v[0], (_Float16)v[1], (_Float16)v[2], (_Float16)v[3]};
            *(half4*)(Wh + (size_t)idx * 4) = h;
        }
    }
}

// K2: raw matmul partial P = x @ W^T over K-range [z*KPB, (z+1)*KPB)
// m97-style: 128x128 tile, BK=64, global_load_lds w=16, 4 waves of 4x4 16x16x32 f16 MFMA
template<int KPB>
__global__ __launch_bounds__(256, 4) void k_gemm(
    const _Float16* __restrict__ A,
    const _Float16* __restrict__ W,
    float* __restrict__ P0,
    float* __restrict__ P1)
{
    __shared__ __align__(16) _Float16 As[128 * 64];
    __shared__ __align__(16) _Float16 Bs[128 * 64];
    int tid = threadIdx.x;
    int lane = tid & 63;
    int w = tid >> 6;
    int wm = (w >> 1) * 64, wn = (w & 1) * 64;
    int bm0 = blockIdx.y * 128, bn0 = blockIdx.x * 128;
    float* P = (blockIdx.z == 0) ? P0 : P1;
    int kbase = blockIdx.z * KPB;

    floatx4 acc[4][4];
#pragma unroll
    for (int mi = 0; mi < 4; ++mi)
#pragma unroll
        for (int ni = 0; ni < 4; ++ni)
            acc[mi][ni] = (floatx4){0.f, 0.f, 0.f, 0.f};

    for (int k0 = 0; k0 < KPB; k0 += 64) {
#pragma unroll
        for (int i = 0; i < 4; ++i) {
            int e = (i * 256 + tid) * 8;     // element index within 128x64 tile
            int r = e >> 6, kk = e & 63;
            __builtin_amdgcn_global_load_lds(
                (gptr_t)(A + (size_t)(bm0 + r) * D_IN + kbase + k0 + kk),
                (lptr_t)(As + e), 16, 0, 0);
            __builtin_amdgcn_global_load_lds(
                (gptr_t)(W + (size_t)(bn0 + r) * D_IN + kbase + k0 + kk),
                (lptr_t)(Bs + e), 16, 0, 0);
        }
        __syncthreads();
#pragma unroll
        for (int ks = 0; ks < 64; ks += 32) {
            int kq = ks + (lane >> 4) * 8;
            half8 afr[4], bfr[4];
#pragma unroll
            for (int mi = 0; mi < 4; ++mi)
                afr[mi] = *(const half8*)(As + (wm + mi * 16 + (lane & 15)) * 64 + kq);
#pragma unroll
            for (int ni = 0; ni < 4; ++ni)
                bfr[ni] = *(const half8*)(Bs + (wn + ni * 16 + (lane & 15)) * 64 + kq);
#pragma unroll
            for (int mi = 0; mi < 4; ++mi)
#pragma unroll
                for (int ni = 0; ni < 4; ++ni)
                    acc[mi][ni] = __builtin_amdgcn_mfma_f32_16x16x32_f16(
                        afr[mi], bfr[ni], acc[mi][ni], 0, 0, 0);
        }
        __syncthreads();
    }
    // epilogue: raw f32 store. C/D layout col=lane&15, row=(lane>>4)*4+r
#pragma unroll
    for (int mi = 0; mi < 4; ++mi) {
#pragma unroll
        for (int r = 0; r < 4; ++r) {
            int gm = bm0 + wm + mi * 16 + (lane >> 4) * 4 + r;
#pragma unroll
            for (int ni = 0; ni < 4; ++ni) {
                int gn = bn0 + wn + ni * 16 + (lane & 15);
                P[(size_t)gm * D_OUT + gn] = acc[mi][ni][r];
            }
        }
    }
}

// K3: per row b: p = P0[b]+P1[b]; h = f_b*p + bias (f_b from n2x,c);
//     reduce pp, p.bias, p.a_k, bb, bias.a_k, ||a_k||^2 -> closed-form Mobius
//     coefficients -> out[b,:] = cp*p + cb*bias + sum_k ca_k*a_k  (in place on d_out)
__global__ __launch_bounds__(256) void k_mobius(
    const float* __restrict__ P1,
    const float* __restrict__ bias,
    const float* __restrict__ anchors,
    const float* __restrict__ tv,
    const float* __restrict__ aw,
    const float* __restrict__ n2x,
    const float* __restrict__ scal,
    int split,
    float* __restrict__ out)
{
    int tid = threadIdx.x, w = tid >> 6, lane = tid & 63;
    size_t rowoff = (size_t)blockIdx.x * D_OUT;
    float pf[8], bf[8];
    *(floatx4*)(pf)     = *(const floatx4*)(out + rowoff + tid * 8);
    *(floatx4*)(pf + 4) = *(const floatx4*)(out + rowoff + tid * 8 + 4);
    if (split == 2) {
        floatx4 q0 = *(const floatx4*)(P1 + rowoff + tid * 8);
        floatx4 q1 = *(const floatx4*)(P1 + rowoff + tid * 8 + 4);
#pragma unroll
        for (int j = 0; j < 4; ++j) { pf[j] += q0[j]; pf[4 + j] += q1[j]; }
    }
    *(floatx4*)(bf)     = *(const floatx4*)(bias + tid * 8);
    *(floatx4*)(bf + 4) = *(const floatx4*)(bias + tid * 8 + 4);
    float af[KANCH][8];
#pragma unroll
    for (int k = 0; k < KANCH; ++k) {
        *(floatx4*)(af[k])     = *(const floatx4*)(anchors + (size_t)k * D_OUT + tid * 8);
        *(floatx4*)(af[k] + 4) = *(const floatx4*)(anchors + (size_t)k * D_OUT + tid * 8 + 4);
    }
    // v: 0 pp, 1 pb, 2..5 pa_k, 6 bb, 7..10 ba_k, 11..14 aa_k
    float v[15];
#pragma unroll
    for (int q = 0; q < 15; ++q) v[q] = 0.f;
#pragma unroll
    for (int j = 0; j < 8; ++j) {
        v[0] += pf[j] * pf[j];
        v[1] += pf[j] * bf[j];
        v[6] += bf[j] * bf[j];
#pragma unroll
        for (int k = 0; k < KANCH; ++k) {
            v[2 + k]  += pf[j] * af[k][j];
            v[7 + k]  += bf[j] * af[k][j];
            v[11 + k] += af[k][j] * af[k][j];
        }
    }
#pragma unroll
    for (int off = 32; off; off >>= 1)
#pragma unroll
        for (int q = 0; q < 15; ++q) v[q] += __shfl_down(v[q], off);
    __shared__ float red[4][15];
    if (lane == 0)
#pragma unroll
        for (int q = 0; q < 15; ++q) red[w][q] = v[q];
    __syncthreads();
    __shared__ float cf[2 + KANCH];   // 0: *p, 1: *bias, 2..: *a_k
    if (tid == 0) {
        float t[15];
#pragma unroll
        for (int q = 0; q < 15; ++q)
            t[q] = red[0][q] + red[1][q] + red[2][q] + red[3][q];
        float c = scal[0] * (1.0f / (float)B_ROWS);   // BASE_CURVATURE=1
        float sc = sqrtf(c);
        // f_b = artanh(clip(sc*||x_b||)) / (sc*||x_b||)
        float nx = fmaxf(sqrtf(n2x[blockIdx.x]), 1e-6f);
        float ax = sc * nx;
        float zx = fminf(fmaxf(ax, -1.f + 1e-5f), 1.f - 1e-5f);
        float f = atanhf(zx) / ax;
        // h = f*p + bias reconstructions
        float hh = f * f * t[0] + 2.f * f * t[1] + t[6];
        float ha[KANCH];
        for (int k = 0; k < KANCH; ++k) ha[k] = f * t[2 + k] + t[7 + k];
        // softmax(anchor_weights)
        float mx = -1e30f;
        for (int k = 0; k < KANCH; ++k) mx = fmaxf(mx, aw[k]);
        float se = 0.f, wk[KANCH];
        for (int k = 0; k < KANCH; ++k) { wk[k] = expf(aw[k] - mx); se += wk[k]; }
        for (int k = 0; k < KANCH; ++k) wk[k] /= se;
        // y = expmap0(h) = gy*h
        float nh = fmaxf(sqrtf(hh), 1e-6f);
        float snh = sc * nh;
        float gy = tanhf(snh) / snh;
        float x2 = gy * gy * hh;           // ||y||^2
        float B1 = 1.f - c * x2;
        float ch = 0.f;
        for (int k = 0; k < KANCH; ++k) {
            float y2 = t[11 + k];          // ||a_k||^2
            float dy = gy * ha[k];         // dot(y, a_k)
            float xy1 = -dy;               // mobius_add(-y, a)
            float A1 = 1.f + 2.f * c * xy1 + c * y2;
            float den1 = fmaxf(1.f + 2.f * c * xy1 + c * c * x2 * y2, 1e-6f);
            float al = -A1 / den1, be = B1 / den1;   // diff = al*y + be*a
            float nd2 = fmaxf(al * al * x2 + 2.f * al * be * dy + be * be * y2, 0.f);
            float nd = fmaxf(sqrtf(nd2), 1e-6f);
            float snd = sc * nd;
            float zc = fminf(fmaxf(snd, -1.f + 1e-5f), 1.f - 1e-5f);
            float s = tanhf(tv[k] * atanhf(zc)) / snd;  // step = s*diff
            float y2s = s * s * nd2;
            float xys = s * (al * x2 + be * dy);
            float A2 = 1.f + 2.f * c * xys + c * y2s;
            float den2 = fmaxf(1.f + 2.f * c * xys + c * c * x2 * y2s, 1e-6f);
            float Cy  = (A2 + B1 * s * al) / den2;   // g = Cy*y + Cak*a
            float Cak = (B1 * s * be) / den2;
            ch += wk[k] * Cy;
            cf[2 + k] = wk[k] * Cak;
        }
        float c0 = gy * ch;   // multiplies h = f*p + bias
        cf[0] = c0 * f;
        cf[1] = c0;
    }
    __syncthreads();
    float cp = cf[0], cb_ = cf[1];
    float o[8];
#pragma unroll
    for (int j = 0; j < 8; ++j) {
        float val = cp * pf[j] + cb_ * bf[j];
#pragma unroll
        for (int k = 0; k < KANCH; ++k) val += cf[2 + k] * af[k][j];
        o[j] = val;
    }
    *(floatx4*)(out + rowoff + tid * 8)     = *(floatx4*)(o);
    *(floatx4*)(out + rowoff + tid * 8 + 4) = *(floatx4*)(o + 4);
}

extern "C" void kernel_launch(void* const* d_in, const int* in_sizes, int n_in,
                              void* d_out, int out_size, void* d_ws, size_t ws_size,
                              hipStream_t stream) {
    const float* x       = (const float*)d_in[0];
    const float* wt      = (const float*)d_in[1];
    const float* bias    = (const float*)d_in[2];
    const float* cw      = (const float*)d_in[3];
    const float* cb      = (const float*)d_in[4];
    const float* anchors = (const float*)d_in[5];
    const float* tv      = (const float*)d_in[6];
    const float* aw      = (const float*)d_in[7];
    float* out = (float*)d_out;

    // ws: Wh fp16 (8.39MB) | xh fp16 (16.78MB) | n2x[4096] | scal[8] | [P1 f32 33.55MB]
    _Float16* Wh = (_Float16*)d_ws;
    _Float16* xh = Wh + (size_t)D_OUT * D_IN;
    float* n2x   = (float*)(xh + (size_t)B_ROWS * D_IN);
    float* scal  = n2x + B_ROWS;
    float* P1    = scal + 8;
    size_t need_split = (size_t)((char*)(P1 + (size_t)B_ROWS * D_OUT) - (char*)d_ws);
    int split = (ws_size >= need_split) ? 2 : 1;

    hipMemsetAsync(scal, 0, sizeof(float), stream);
    k_prep<<<2048, 256, 0, stream>>>(x, wt, cw, cb, xh, Wh, n2x, scal);
    if (split == 2)
        k_gemm<D_IN / 2><<<dim3(D_OUT / 128, B_ROWS / 128, 2), 256, 0, stream>>>(xh, Wh, out, P1);
    else
        k_gemm<D_IN><<<dim3(D_OUT / 128, B_ROWS / 128, 1), 256, 0, stream>>>(xh, Wh, out, P1);
    k_mobius<<<B_ROWS, 256, 0, stream>>>(P1, bias, anchors, tv, aw, n2x, scal, split, out);
}

// Round 5
// 179.411 us; speedup vs baseline: 1.1564x; 1.1564x over previous
//
#include <hip/hip_runtime.h>
#include <stdint.h>

#define B_ROWS 4096
#define D_IN   2048
#define D_OUT  2048
#define KANCH  4

typedef _Float16 half8  __attribute__((ext_vector_type(8)));
typedef _Float16 half4  __attribute__((ext_vector_type(4)));
typedef float    floatx4 __attribute__((ext_vector_type(4)));
typedef const __attribute__((address_space(1))) uint8_t* gptr_t;
typedef __attribute__((address_space(3))) uint8_t* lptr_t;

__device__ __forceinline__ float frcp(float x)   { return __builtin_amdgcn_rcpf(x); }
__device__ __forceinline__ float ftanh(float x)  { float e = __expf(2.f * x); return (e - 1.f) * frcp(e + 1.f); }
__device__ __forceinline__ float fatanh(float z) { return 0.5f * __logf((1.f + z) * frcp(1.f - z)); }

// K1 fused prep:
//  blocks [0,1024): x->fp16, n2x[b]=||x_b||^2, atomicAdd softplus partials -> scal[0]
//  blocks [1024,2048): W->fp16
//  block 2048: static dots  scal[1]=b.b, scal[2+k]=b.a_k, scal[6+k]=a_k.a_k
__global__ __launch_bounds__(256) void k_prep(
    const float* __restrict__ x,
    const float* __restrict__ W,
    const float* __restrict__ cw,
    const float* __restrict__ cb,
    const float* __restrict__ bias,
    const float* __restrict__ anchors,
    _Float16* __restrict__ xh,
    _Float16* __restrict__ Wh,
    float* __restrict__ n2x,
    float* __restrict__ scal)
{
    int tid = threadIdx.x;
    if (blockIdx.x < 1024) {
        int w = tid >> 6, lane = tid & 63;
        int row = blockIdx.x * 4 + w;
        const floatx4* xr = (const floatx4*)(x + (size_t)row * D_IN);
        const floatx4* wr = (const floatx4*)cw;
        _Float16* xo = xh + (size_t)row * D_IN;
        float dot = 0.f, ss = 0.f;
#pragma unroll
        for (int i = 0; i < 8; ++i) {
            int idx = i * 64 + lane;
            floatx4 xv = xr[idx];
            floatx4 wv = wr[idx];
#pragma unroll
            for (int j = 0; j < 4; ++j) {
                dot += xv[j] * wv[j];
                ss  += xv[j] * xv[j];
            }
            half4 h = {(_Float16)xv[0], (_Float16)xv[1], (_Float16)xv[2], (_Float16)xv[3]};
            *(half4*)(xo + idx * 4) = h;
        }
#pragma unroll
        for (int off = 32; off; off >>= 1) {
            dot += __shfl_down(dot, off);
            ss  += __shfl_down(ss, off);
        }
        __shared__ float spw[4];
        if (lane == 0) {
            n2x[row] = ss;
            float z = dot + cb[0];
            spw[w] = (z > 20.f) ? z : log1pf(expf(z));
        }
        __syncthreads();
        if (tid == 0)
            atomicAdd(&scal[0], spw[0] + spw[1] + spw[2] + spw[3]);
    } else if (blockIdx.x < 2048) {
        int blk = blockIdx.x - 1024;
        const floatx4* W4 = (const floatx4*)W;
#pragma unroll
        for (int i = 0; i < 4; ++i) {
            int idx = blk * 1024 + i * 256 + tid;   // float4 index
            floatx4 v = W4[idx];
            half4 h = {(_Float16)v[0], (_Float16)v[1], (_Float16)v[2], (_Float16)v[3]};
            *(half4*)(Wh + (size_t)idx * 4) = h;
        }
    } else {
        // static dots: 9 quantities over D_OUT
        int w = tid >> 6, lane = tid & 63;
        float bf[8], af[KANCH][8];
        *(floatx4*)(bf)     = *(const floatx4*)(bias + tid * 8);
        *(floatx4*)(bf + 4) = *(const floatx4*)(bias + tid * 8 + 4);
#pragma unroll
        for (int k = 0; k < KANCH; ++k) {
            *(floatx4*)(af[k])     = *(const floatx4*)(anchors + (size_t)k * D_OUT + tid * 8);
            *(floatx4*)(af[k] + 4) = *(const floatx4*)(anchors + (size_t)k * D_OUT + tid * 8 + 4);
        }
        float v[9];
#pragma unroll
        for (int q = 0; q < 9; ++q) v[q] = 0.f;
#pragma unroll
        for (int j = 0; j < 8; ++j) {
            v[0] += bf[j] * bf[j];
#pragma unroll
            for (int k = 0; k < KANCH; ++k) {
                v[1 + k] += bf[j] * af[k][j];
                v[5 + k] += af[k][j] * af[k][j];
            }
        }
#pragma unroll
        for (int off = 32; off; off >>= 1)
#pragma unroll
            for (int q = 0; q < 9; ++q) v[q] += __shfl_down(v[q], off);
        __shared__ float red[4][9];
        if (lane == 0)
#pragma unroll
            for (int q = 0; q < 9; ++q) red[w][q] = v[q];
        __syncthreads();
        if (tid == 0)
#pragma unroll
            for (int q = 0; q < 9; ++q)
                scal[1 + q] = red[0][q] + red[1][q] + red[2][q] + red[3][q];
    }
}

// K2: raw matmul partial P = x @ W^T over K-range [z*KPB, (z+1)*KPB)
// m97-style: 128x128 tile, BK=64, global_load_lds w=16, 4 waves of 4x4 16x16x32 f16 MFMA
template<int KPB>
__global__ __launch_bounds__(256, 4) void k_gemm(
    const _Float16* __restrict__ A,
    const _Float16* __restrict__ W,
    float* __restrict__ P0,
    float* __restrict__ P1)
{
    __shared__ __align__(16) _Float16 As[128 * 64];
    __shared__ __align__(16) _Float16 Bs[128 * 64];
    int tid = threadIdx.x;
    int lane = tid & 63;
    int w = tid >> 6;
    int wm = (w >> 1) * 64, wn = (w & 1) * 64;
    int bm0 = blockIdx.y * 128, bn0 = blockIdx.x * 128;
    float* P = (blockIdx.z == 0) ? P0 : P1;
    int kbase = blockIdx.z * KPB;

    floatx4 acc[4][4];
#pragma unroll
    for (int mi = 0; mi < 4; ++mi)
#pragma unroll
        for (int ni = 0; ni < 4; ++ni)
            acc[mi][ni] = (floatx4){0.f, 0.f, 0.f, 0.f};

    for (int k0 = 0; k0 < KPB; k0 += 64) {
#pragma unroll
        for (int i = 0; i < 4; ++i) {
            int e = (i * 256 + tid) * 8;     // element index within 128x64 tile
            int r = e >> 6, kk = e & 63;
            __builtin_amdgcn_global_load_lds(
                (gptr_t)(A + (size_t)(bm0 + r) * D_IN + kbase + k0 + kk),
                (lptr_t)(As + e), 16, 0, 0);
            __builtin_amdgcn_global_load_lds(
                (gptr_t)(W + (size_t)(bn0 + r) * D_IN + kbase + k0 + kk),
                (lptr_t)(Bs + e), 16, 0, 0);
        }
        __syncthreads();
#pragma unroll
        for (int ks = 0; ks < 64; ks += 32) {
            int kq = ks + (lane >> 4) * 8;
            half8 afr[4], bfr[4];
#pragma unroll
            for (int mi = 0; mi < 4; ++mi)
                afr[mi] = *(const half8*)(As + (wm + mi * 16 + (lane & 15)) * 64 + kq);
#pragma unroll
            for (int ni = 0; ni < 4; ++ni)
                bfr[ni] = *(const half8*)(Bs + (wn + ni * 16 + (lane & 15)) * 64 + kq);
#pragma unroll
            for (int mi = 0; mi < 4; ++mi)
#pragma unroll
                for (int ni = 0; ni < 4; ++ni)
                    acc[mi][ni] = __builtin_amdgcn_mfma_f32_16x16x32_f16(
                        afr[mi], bfr[ni], acc[mi][ni], 0, 0, 0);
        }
        __syncthreads();
    }
    // epilogue: raw f32 store. C/D layout col=lane&15, row=(lane>>4)*4+r
#pragma unroll
    for (int mi = 0; mi < 4; ++mi) {
#pragma unroll
        for (int r = 0; r < 4; ++r) {
            int gm = bm0 + wm + mi * 16 + (lane >> 4) * 4 + r;
#pragma unroll
            for (int ni = 0; ni < 4; ++ni) {
                int gn = bn0 + wn + ni * 16 + (lane & 15);
                P[(size_t)gm * D_OUT + gn] = acc[mi][ni][r];
            }
        }
    }
}

// K3: per row b: p = P0[b](+P1[b]); reduce pp, pb, pa_k (6) -> wave-0 computes
//     Mobius coefficients (lanes 0..3 = anchors, fast math) -> combine, in place.
__global__ __launch_bounds__(256) void k_mobius(
    const float* __restrict__ P1,
    const float* __restrict__ bias,
    const float* __restrict__ anchors,
    const float* __restrict__ tv,
    const float* __restrict__ aw,
    const float* __restrict__ n2x,
    const float* __restrict__ scal,
    int split,
    float* __restrict__ out)
{
    int tid = threadIdx.x, w = tid >> 6, lane = tid & 63;
    size_t rowoff = (size_t)blockIdx.x * D_OUT;
    float pf[8], bf[8];
    *(floatx4*)(pf)     = *(const floatx4*)(out + rowoff + tid * 8);
    *(floatx4*)(pf + 4) = *(const floatx4*)(out + rowoff + tid * 8 + 4);
    if (split == 2) {
        floatx4 q0 = *(const floatx4*)(P1 + rowoff + tid * 8);
        floatx4 q1 = *(const floatx4*)(P1 + rowoff + tid * 8 + 4);
#pragma unroll
        for (int j = 0; j < 4; ++j) { pf[j] += q0[j]; pf[4 + j] += q1[j]; }
    }
    *(floatx4*)(bf)     = *(const floatx4*)(bias + tid * 8);
    *(floatx4*)(bf + 4) = *(const floatx4*)(bias + tid * 8 + 4);
    float af[KANCH][8];
#pragma unroll
    for (int k = 0; k < KANCH; ++k) {
        *(floatx4*)(af[k])     = *(const floatx4*)(anchors + (size_t)k * D_OUT + tid * 8);
        *(floatx4*)(af[k] + 4) = *(const floatx4*)(anchors + (size_t)k * D_OUT + tid * 8 + 4);
    }
    // v: 0 pp, 1 pb, 2..5 pa_k
    float v[6];
#pragma unroll
    for (int q = 0; q < 6; ++q) v[q] = 0.f;
#pragma unroll
    for (int j = 0; j < 8; ++j) {
        v[0] += pf[j] * pf[j];
        v[1] += pf[j] * bf[j];
#pragma unroll
        for (int k = 0; k < KANCH; ++k) v[2 + k] += pf[j] * af[k][j];
    }
#pragma unroll
    for (int off = 32; off; off >>= 1)
#pragma unroll
        for (int q = 0; q < 6; ++q) v[q] += __shfl_down(v[q], off);
    __shared__ float red[4][6];
    __shared__ float cf[2 + KANCH];   // 0: *p, 1: *bias, 2..: *a_k
    if (lane == 0)
#pragma unroll
        for (int q = 0; q < 6; ++q) red[w][q] = v[q];
    __syncthreads();
    if (w == 0) {
        // all 64 lanes run this; lanes 0..3 own anchor k=lane&3
        int k = lane & 3;
        float pp = red[0][0] + red[1][0] + red[2][0] + red[3][0];
        float pb = red[0][1] + red[1][1] + red[2][1] + red[3][1];
        float pa = red[0][2 + k] + red[1][2 + k] + red[2][2 + k] + red[3][2 + k];
        float bb = scal[1];
        float ba = scal[2 + k];
        float aa = scal[6 + k];
        float c = scal[0] * (1.0f / (float)B_ROWS);   // BASE_CURVATURE=1
        float sc = __builtin_amdgcn_sqrtf(c);
        // f_b = artanh(clip(sc*||x_b||)) / (sc*||x_b||)
        float nx = fmaxf(__builtin_amdgcn_sqrtf(n2x[blockIdx.x]), 1e-6f);
        float ax = sc * nx;
        float zx = fminf(fmaxf(ax, -1.f + 1e-5f), 1.f - 1e-5f);
        float f = fatanh(zx) * frcp(ax);
        // h = f*p + bias reconstructions
        float hh = f * f * pp + 2.f * f * pb + bb;
        float ha = f * pa + ba;
        // softmax weight for own anchor
        float ek = __expf(aw[k]);
        float se = ek;
        se += __shfl_xor(se, 1);
        se += __shfl_xor(se, 2);
        float wk = ek * frcp(se);
        // y = expmap0(h) = gy*h
        float nh = fmaxf(__builtin_amdgcn_sqrtf(hh), 1e-6f);
        float snh = sc * nh;
        float gy = ftanh(snh) * frcp(snh);
        float x2 = gy * gy * hh;           // ||y||^2
        float B1 = 1.f - c * x2;
        // per-anchor closed-form coefficients
        float y2 = aa;
        float dy = gy * ha;                // dot(y, a_k)
        float A1 = 1.f - 2.f * c * dy + c * y2;
        float den1 = fmaxf(1.f - 2.f * c * dy + c * c * x2 * y2, 1e-6f);
        float rd1 = frcp(den1);
        float al = -A1 * rd1, be = B1 * rd1;         // diff = al*y + be*a
        float nd2 = fmaxf(al * al * x2 + 2.f * al * be * dy + be * be * y2, 0.f);
        float nd = fmaxf(__builtin_amdgcn_sqrtf(nd2), 1e-6f);
        float snd = sc * nd;
        float zc = fminf(fmaxf(snd, -1.f + 1e-5f), 1.f - 1e-5f);
        float s = ftanh(tv[k] * fatanh(zc)) * frcp(snd);  // step = s*diff
        float y2s = s * s * nd2;
        float xys = s * (al * x2 + be * dy);
        float A2 = 1.f + 2.f * c * xys + c * y2s;
        float den2 = fmaxf(1.f + 2.f * c * xys + c * c * x2 * y2s, 1e-6f);
        float rd2 = frcp(den2);
        float Cy  = (A2 + B1 * s * al) * rd2;        // g = Cy*y + Cak*a
        float Cak = (B1 * s * be) * rd2;
        float chk = wk * Cy;
        chk += __shfl_xor(chk, 1);
        chk += __shfl_xor(chk, 2);                   // lanes 0..3: sum_k wk*Cy
        if (lane == 0) {
            float c0 = gy * chk;                     // multiplies h = f*p + bias
            cf[0] = c0 * f;
            cf[1] = c0;
        }
        if (lane < 4) cf[2 + lane] = wk * Cak;
    }
    __syncthreads();
    float cp = cf[0], cb_ = cf[1];
    float o[8];
#pragma unroll
    for (int j = 0; j < 8; ++j) {
        float val = cp * pf[j] + cb_ * bf[j];
#pragma unroll
        for (int k = 0; k < KANCH; ++k) val += cf[2 + k] * af[k][j];
        o[j] = val;
    }
    *(floatx4*)(out + rowoff + tid * 8)     = *(floatx4*)(o);
    *(floatx4*)(out + rowoff + tid * 8 + 4) = *(floatx4*)(o + 4);
}

extern "C" void kernel_launch(void* const* d_in, const int* in_sizes, int n_in,
                              void* d_out, int out_size, void* d_ws, size_t ws_size,
                              hipStream_t stream) {
    const float* x       = (const float*)d_in[0];
    const float* wt      = (const float*)d_in[1];
    const float* bias    = (const float*)d_in[2];
    const float* cw      = (const float*)d_in[3];
    const float* cb      = (const float*)d_in[4];
    const float* anchors = (const float*)d_in[5];
    const float* tv      = (const float*)d_in[6];
    const float* aw      = (const float*)d_in[7];
    float* out = (float*)d_out;

    // ws: Wh fp16 (8.39MB) | xh fp16 (16.78MB) | n2x[4096] | scal[16] | [P1 f32 33.55MB]
    _Float16* Wh = (_Float16*)d_ws;
    _Float16* xh = Wh + (size_t)D_OUT * D_IN;
    float* n2x   = (float*)(xh + (size_t)B_ROWS * D_IN);
    float* scal  = n2x + B_ROWS;
    float* P1    = scal + 16;
    size_t need_split = (size_t)((char*)(P1 + (size_t)B_ROWS * D_OUT) - (char*)d_ws);
    int split = (ws_size >= need_split) ? 2 : 1;

    hipMemsetAsync(scal, 0, sizeof(float), stream);
    k_prep<<<2049, 256, 0, stream>>>(x, wt, cw, cb, bias, anchors, xh, Wh, n2x, scal);
    if (split == 2)
        k_gemm<D_IN / 2><<<dim3(D_OUT / 128, B_ROWS / 128, 2), 256, 0, stream>>>(xh, Wh, out, P1);
    else
        k_gemm<D_IN><<<dim3(D_OUT / 128, B_ROWS / 128, 1), 256, 0, stream>>>(xh, Wh, out, P1);
    k_mobius<<<B_ROWS, 256, 0, stream>>>(P1, bias, anchors, tv, aw, n2x, scal, split, out);
}

// Round 6
// 162.530 us; speedup vs baseline: 1.2765x; 1.1039x over previous
//
#include <hip/hip_runtime.h>
#include <stdint.h>

#define B_ROWS 4096
#define D_IN   2048
#define D_OUT  2048
#define KANCH  4

typedef _Float16 half8  __attribute__((ext_vector_type(8)));
typedef _Float16 half4  __attribute__((ext_vector_type(4)));
typedef float    floatx4 __attribute__((ext_vector_type(4)));
typedef const __attribute__((address_space(1))) uint8_t* gptr_t;
typedef __attribute__((address_space(3))) uint8_t* lptr_t;

__device__ __forceinline__ float frcp(float x)   { return __builtin_amdgcn_rcpf(x); }
__device__ __forceinline__ float ftanh(float x)  { float e = __expf(2.f * x); return (e - 1.f) * frcp(e + 1.f); }
__device__ __forceinline__ float fatanh(float z) { return 0.5f * __logf((1.f + z) * frcp(1.f - z)); }

// K1 fused prep:
//  blocks [0,1024): x->fp16, n2x[b]=||x_b||^2, block softplus partial -> spart[blk]
//  blocks [1024,2048): W->fp16
//  block 2048: static dots  scal[1]=b.b, scal[2+k]=b.a_k, scal[6+k]=a_k.a_k
__global__ __launch_bounds__(256) void k_prep(
    const float* __restrict__ x,
    const float* __restrict__ W,
    const float* __restrict__ cw,
    const float* __restrict__ cb,
    const float* __restrict__ bias,
    const float* __restrict__ anchors,
    _Float16* __restrict__ xh,
    _Float16* __restrict__ Wh,
    float* __restrict__ n2x,
    float* __restrict__ spart,
    float* __restrict__ scal)
{
    int tid = threadIdx.x;
    if (blockIdx.x < 1024) {
        int w = tid >> 6, lane = tid & 63;
        int row = blockIdx.x * 4 + w;
        const floatx4* xr = (const floatx4*)(x + (size_t)row * D_IN);
        const floatx4* wr = (const floatx4*)cw;
        _Float16* xo = xh + (size_t)row * D_IN;
        float dot = 0.f, ss = 0.f;
#pragma unroll
        for (int i = 0; i < 8; ++i) {
            int idx = i * 64 + lane;
            floatx4 xv = xr[idx];
            floatx4 wv = wr[idx];
#pragma unroll
            for (int j = 0; j < 4; ++j) {
                dot += xv[j] * wv[j];
                ss  += xv[j] * xv[j];
            }
            half4 h = {(_Float16)xv[0], (_Float16)xv[1], (_Float16)xv[2], (_Float16)xv[3]};
            *(half4*)(xo + idx * 4) = h;
        }
#pragma unroll
        for (int off = 32; off; off >>= 1) {
            dot += __shfl_down(dot, off);
            ss  += __shfl_down(ss, off);
        }
        __shared__ float spw[4];
        if (lane == 0) {
            n2x[row] = ss;
            float z = dot + cb[0];
            spw[w] = (z > 20.f) ? z : log1pf(expf(z));
        }
        __syncthreads();
        if (tid == 0)
            spart[blockIdx.x] = spw[0] + spw[1] + spw[2] + spw[3];
    } else if (blockIdx.x < 2048) {
        int blk = blockIdx.x - 1024;
        const floatx4* W4 = (const floatx4*)W;
#pragma unroll
        for (int i = 0; i < 4; ++i) {
            int idx = blk * 1024 + i * 256 + tid;   // float4 index
            floatx4 v = W4[idx];
            half4 h = {(_Float16)v[0], (_Float16)v[1], (_Float16)v[2], (_Float16)v[3]};
            *(half4*)(Wh + (size_t)idx * 4) = h;
        }
    } else {
        // static dots: 9 quantities over D_OUT
        int w = tid >> 6, lane = tid & 63;
        float bf[8], af[KANCH][8];
        *(floatx4*)(bf)     = *(const floatx4*)(bias + tid * 8);
        *(floatx4*)(bf + 4) = *(const floatx4*)(bias + tid * 8 + 4);
#pragma unroll
        for (int k = 0; k < KANCH; ++k) {
            *(floatx4*)(af[k])     = *(const floatx4*)(anchors + (size_t)k * D_OUT + tid * 8);
            *(floatx4*)(af[k] + 4) = *(const floatx4*)(anchors + (size_t)k * D_OUT + tid * 8 + 4);
        }
        float v[9];
#pragma unroll
        for (int q = 0; q < 9; ++q) v[q] = 0.f;
#pragma unroll
        for (int j = 0; j < 8; ++j) {
            v[0] += bf[j] * bf[j];
#pragma unroll
            for (int k = 0; k < KANCH; ++k) {
                v[1 + k] += bf[j] * af[k][j];
                v[5 + k] += af[k][j] * af[k][j];
            }
        }
#pragma unroll
        for (int off = 32; off; off >>= 1)
#pragma unroll
            for (int q = 0; q < 9; ++q) v[q] += __shfl_down(v[q], off);
        __shared__ float red[4][9];
        if (lane == 0)
#pragma unroll
            for (int q = 0; q < 9; ++q) red[w][q] = v[q];
        __syncthreads();
        if (tid == 0)
#pragma unroll
            for (int q = 0; q < 9; ++q)
                scal[1 + q] = red[0][q] + red[1][q] + red[2][q] + red[3][q];
    }
}

// K2: matmul partial P = x @ W^T over K-range [z*KPB, (z+1)*KPB), stored fp16
// m97-style: 128x128 tile, BK=64, global_load_lds w=16, 4 waves of 4x4 16x16x32 f16 MFMA
template<int KPB>
__global__ __launch_bounds__(256, 4) void k_gemm(
    const _Float16* __restrict__ A,
    const _Float16* __restrict__ W,
    _Float16* __restrict__ P0,
    _Float16* __restrict__ P1)
{
    __shared__ __align__(16) _Float16 As[128 * 64];
    __shared__ __align__(16) _Float16 Bs[128 * 64];
    int tid = threadIdx.x;
    int lane = tid & 63;
    int w = tid >> 6;
    int wm = (w >> 1) * 64, wn = (w & 1) * 64;
    int bm0 = blockIdx.y * 128, bn0 = blockIdx.x * 128;
    _Float16* P = (blockIdx.z == 0) ? P0 : P1;
    int kbase = blockIdx.z * KPB;

    floatx4 acc[4][4];
#pragma unroll
    for (int mi = 0; mi < 4; ++mi)
#pragma unroll
        for (int ni = 0; ni < 4; ++ni)
            acc[mi][ni] = (floatx4){0.f, 0.f, 0.f, 0.f};

    for (int k0 = 0; k0 < KPB; k0 += 64) {
#pragma unroll
        for (int i = 0; i < 4; ++i) {
            int e = (i * 256 + tid) * 8;     // element index within 128x64 tile
            int r = e >> 6, kk = e & 63;
            __builtin_amdgcn_global_load_lds(
                (gptr_t)(A + (size_t)(bm0 + r) * D_IN + kbase + k0 + kk),
                (lptr_t)(As + e), 16, 0, 0);
            __builtin_amdgcn_global_load_lds(
                (gptr_t)(W + (size_t)(bn0 + r) * D_IN + kbase + k0 + kk),
                (lptr_t)(Bs + e), 16, 0, 0);
        }
        __syncthreads();
#pragma unroll
        for (int ks = 0; ks < 64; ks += 32) {
            int kq = ks + (lane >> 4) * 8;
            half8 afr[4], bfr[4];
#pragma unroll
            for (int mi = 0; mi < 4; ++mi)
                afr[mi] = *(const half8*)(As + (wm + mi * 16 + (lane & 15)) * 64 + kq);
#pragma unroll
            for (int ni = 0; ni < 4; ++ni)
                bfr[ni] = *(const half8*)(Bs + (wn + ni * 16 + (lane & 15)) * 64 + kq);
#pragma unroll
            for (int mi = 0; mi < 4; ++mi)
#pragma unroll
                for (int ni = 0; ni < 4; ++ni)
                    acc[mi][ni] = __builtin_amdgcn_mfma_f32_16x16x32_f16(
                        afr[mi], bfr[ni], acc[mi][ni], 0, 0, 0);
        }
        __syncthreads();
    }
    // epilogue: fp16 store. C/D layout col=lane&15, row=(lane>>4)*4+r
#pragma unroll
    for (int mi = 0; mi < 4; ++mi) {
#pragma unroll
        for (int r = 0; r < 4; ++r) {
            int gm = bm0 + wm + mi * 16 + (lane >> 4) * 4 + r;
#pragma unroll
            for (int ni = 0; ni < 4; ++ni) {
                int gn = bn0 + wn + ni * 16 + (lane & 15);
                P[(size_t)gm * D_OUT + gn] = (_Float16)acc[mi][ni][r];
            }
        }
    }
}

// K3: per row b: p = P0[b](+P1[b]); reduce pp,pb,pa_k + spart-sum (7 qtys) ->
//     wave-0 computes Mobius coefficients (lanes 0..3 = anchors, fast math) ->
//     out[b,:] = cp*p + cb*bias + sum_k ca_k*a_k
__global__ __launch_bounds__(256) void k_mobius(
    const _Float16* __restrict__ P0,
    const _Float16* __restrict__ P1,
    const float* __restrict__ bias,
    const float* __restrict__ anchors,
    const float* __restrict__ tv,
    const float* __restrict__ aw,
    const float* __restrict__ n2x,
    const float* __restrict__ spart,
    const float* __restrict__ scal,
    int split,
    float* __restrict__ out)
{
    int tid = threadIdx.x, w = tid >> 6, lane = tid & 63;
    size_t rowoff = (size_t)blockIdx.x * D_OUT;
    float pf[8], bf[8];
    {
        half8 p = *(const half8*)(P0 + rowoff + tid * 8);
#pragma unroll
        for (int j = 0; j < 8; ++j) pf[j] = (float)p[j];
    }
    if (split == 2) {
        half8 q = *(const half8*)(P1 + rowoff + tid * 8);
#pragma unroll
        for (int j = 0; j < 8; ++j) pf[j] += (float)q[j];
    }
    *(floatx4*)(bf)     = *(const floatx4*)(bias + tid * 8);
    *(floatx4*)(bf + 4) = *(const floatx4*)(bias + tid * 8 + 4);
    float af[KANCH][8];
#pragma unroll
    for (int k = 0; k < KANCH; ++k) {
        *(floatx4*)(af[k])     = *(const floatx4*)(anchors + (size_t)k * D_OUT + tid * 8);
        *(floatx4*)(af[k] + 4) = *(const floatx4*)(anchors + (size_t)k * D_OUT + tid * 8 + 4);
    }
    // v: 0 pp, 1 pb, 2..5 pa_k, 6 spart partial
    float v[7];
#pragma unroll
    for (int q = 0; q < 7; ++q) v[q] = 0.f;
    {
        floatx4 s4 = ((const floatx4*)spart)[tid];   // 1024 floats, 4 per thread
        v[6] = s4[0] + s4[1] + s4[2] + s4[3];
    }
#pragma unroll
    for (int j = 0; j < 8; ++j) {
        v[0] += pf[j] * pf[j];
        v[1] += pf[j] * bf[j];
#pragma unroll
        for (int k = 0; k < KANCH; ++k) v[2 + k] += pf[j] * af[k][j];
    }
#pragma unroll
    for (int off = 32; off; off >>= 1)
#pragma unroll
        for (int q = 0; q < 7; ++q) v[q] += __shfl_down(v[q], off);
    __shared__ float red[4][7];
    __shared__ float cf[2 + KANCH];   // 0: *p, 1: *bias, 2..: *a_k
    if (lane == 0)
#pragma unroll
        for (int q = 0; q < 7; ++q) red[w][q] = v[q];
    __syncthreads();
    if (w == 0) {
        // all 64 lanes run this; lanes 0..3 own anchor k=lane&3
        int k = lane & 3;
        float pp = red[0][0] + red[1][0] + red[2][0] + red[3][0];
        float pb = red[0][1] + red[1][1] + red[2][1] + red[3][1];
        float pa = red[0][2 + k] + red[1][2 + k] + red[2][2 + k] + red[3][2 + k];
        float spsum = red[0][6] + red[1][6] + red[2][6] + red[3][6];
        float bb = scal[1];
        float ba = scal[2 + k];
        float aa = scal[6 + k];
        float c = spsum * (1.0f / (float)B_ROWS);   // BASE_CURVATURE=1
        float sc = __builtin_amdgcn_sqrtf(c);
        // f_b = artanh(clip(sc*||x_b||)) / (sc*||x_b||)
        float nx = fmaxf(__builtin_amdgcn_sqrtf(n2x[blockIdx.x]), 1e-6f);
        float ax = sc * nx;
        float zx = fminf(fmaxf(ax, -1.f + 1e-5f), 1.f - 1e-5f);
        float f = fatanh(zx) * frcp(ax);
        // h = f*p + bias reconstructions
        float hh = f * f * pp + 2.f * f * pb + bb;
        float ha = f * pa + ba;
        // softmax weight for own anchor
        float ek = __expf(aw[k]);
        float se = ek;
        se += __shfl_xor(se, 1);
        se += __shfl_xor(se, 2);
        float wk = ek * frcp(se);
        // y = expmap0(h) = gy*h
        float nh = fmaxf(__builtin_amdgcn_sqrtf(hh), 1e-6f);
        float snh = sc * nh;
        float gy = ftanh(snh) * frcp(snh);
        float x2 = gy * gy * hh;           // ||y||^2
        float B1 = 1.f - c * x2;
        // per-anchor closed-form coefficients
        float y2 = aa;
        float dy = gy * ha;                // dot(y, a_k)
        float A1 = 1.f - 2.f * c * dy + c * y2;
        float den1 = fmaxf(1.f - 2.f * c * dy + c * c * x2 * y2, 1e-6f);
        float rd1 = frcp(den1);
        float al = -A1 * rd1, be = B1 * rd1;         // diff = al*y + be*a
        float nd2 = fmaxf(al * al * x2 + 2.f * al * be * dy + be * be * y2, 0.f);
        float nd = fmaxf(__builtin_amdgcn_sqrtf(nd2), 1e-6f);
        float snd = sc * nd;
        float zc = fminf(fmaxf(snd, -1.f + 1e-5f), 1.f - 1e-5f);
        float s = ftanh(tv[k] * fatanh(zc)) * frcp(snd);  // step = s*diff
        float y2s = s * s * nd2;
        float xys = s * (al * x2 + be * dy);
        float A2 = 1.f + 2.f * c * xys + c * y2s;
        float den2 = fmaxf(1.f + 2.f * c * xys + c * c * x2 * y2s, 1e-6f);
        float rd2 = frcp(den2);
        float Cy  = (A2 + B1 * s * al) * rd2;        // g = Cy*y + Cak*a
        float Cak = (B1 * s * be) * rd2;
        float chk = wk * Cy;
        chk += __shfl_xor(chk, 1);
        chk += __shfl_xor(chk, 2);                   // lanes 0..3: sum_k wk*Cy
        if (lane == 0) {
            float c0 = gy * chk;                     // multiplies h = f*p + bias
            cf[0] = c0 * f;
            cf[1] = c0;
        }
        if (lane < 4) cf[2 + lane] = wk * Cak;
    }
    __syncthreads();
    float cp = cf[0], cb_ = cf[1];
    float o[8];
#pragma unroll
    for (int j = 0; j < 8; ++j) {
        float val = cp * pf[j] + cb_ * bf[j];
#pragma unroll
        for (int k = 0; k < KANCH; ++k) val += cf[2 + k] * af[k][j];
        o[j] = val;
    }
    *(floatx4*)(out + rowoff + tid * 8)     = *(floatx4*)(o);
    *(floatx4*)(out + rowoff + tid * 8 + 4) = *(floatx4*)(o + 4);
}

extern "C" void kernel_launch(void* const* d_in, const int* in_sizes, int n_in,
                              void* d_out, int out_size, void* d_ws, size_t ws_size,
                              hipStream_t stream) {
    const float* x       = (const float*)d_in[0];
    const float* wt      = (const float*)d_in[1];
    const float* bias    = (const float*)d_in[2];
    const float* cw      = (const float*)d_in[3];
    const float* cb      = (const float*)d_in[4];
    const float* anchors = (const float*)d_in[5];
    const float* tv      = (const float*)d_in[6];
    const float* aw      = (const float*)d_in[7];
    float* out = (float*)d_out;

    // ws: Wh fp16 8.39MB | xh fp16 16.78MB | n2x[4096] | spart[1024] | scal[16]
    //     | P0 fp16 16.78MB | [P1 fp16 16.78MB]   (~58.74 MB for split-2)
    _Float16* Wh = (_Float16*)d_ws;
    _Float16* xh = Wh + (size_t)D_OUT * D_IN;
    float* n2x   = (float*)(xh + (size_t)B_ROWS * D_IN);
    float* spart = n2x + B_ROWS;
    float* scal  = spart + 1024;
    _Float16* P0 = (_Float16*)(scal + 16);
    _Float16* P1 = P0 + (size_t)B_ROWS * D_OUT;
    size_t need2 = (size_t)((char*)(P1 + (size_t)B_ROWS * D_OUT) - (char*)d_ws);
    int split = (ws_size >= need2) ? 2 : 1;

    k_prep<<<2049, 256, 0, stream>>>(x, wt, cw, cb, bias, anchors, xh, Wh, n2x, spart, scal);
    if (split == 2)
        k_gemm<D_IN / 2><<<dim3(D_OUT / 128, B_ROWS / 128, 2), 256, 0, stream>>>(xh, Wh, P0, P1);
    else
        k_gemm<D_IN><<<dim3(D_OUT / 128, B_ROWS / 128, 1), 256, 0, stream>>>(xh, Wh, P0, P1);
    k_mobius<<<B_ROWS, 256, 0, stream>>>(P0, P1, bias, anchors, tv, aw, n2x, spart, scal, split, out);
}